// Round 3
// baseline (10082.944 us; speedup 1.0000x reference)
//
#include <hip/hip_runtime.h>
#include <hip/hip_cooperative_groups.h>
#include <cmath>

namespace cg = cooperative_groups;

// Problem constants
#define BB   16
#define LKK  64
#define LQQ  64
#define DD   300
#define HH   512
#define H2   1024
#define G4   2048
#define G8   4096
#define VV   10000

__device__ __forceinline__ float sigmoidf_(float x) { return 1.f / (1.f + expf(-x)); }

// ---------------- reverse source indices for backward encoder ----------------
__global__ void rev_idx_kernel(const int* __restrict__ src, int* __restrict__ rev) {
    int tid = blockIdx.x * blockDim.x + threadIdx.x;
    if (tid < BB * LKK) {
        int b = tid / LKK, t = tid % LKK;
        rev[tid] = src[b * LKK + (LKK - 1 - t)];
    }
}

// ---------------- transpose (fallback path): out[k*N+n] = in[n*K+k] ----------
__global__ void transpose_kernel(const float* __restrict__ in, float* __restrict__ out,
                                 int N, int K) {
    long tid = (long)blockIdx.x * blockDim.x + threadIdx.x;
    long total = (long)N * K;
    if (tid < total) {
        int n = (int)(tid % N);
        int k = (int)(tid / N);
        out[(long)k * N + n] = in[(long)n * K + k];
    }
}

// ---------------- generic NT GEMM: C[m,n] = sum_k A[m,k]*Bw[n,k] + bias[n] ----
__global__ __launch_bounds__(256)
void gemm_nt_kernel(const float* __restrict__ A, const int* __restrict__ gidx, int lda,
                    const float* __restrict__ Bw, int ldb,
                    const float* __restrict__ bias,
                    float* __restrict__ C, int ldc,
                    int N, int K, int act) {
    __shared__ float As[16][68];
    __shared__ float Bs[16][68];
    int m0 = blockIdx.x * 64;
    int n0 = blockIdx.y * 64;
    int tid = threadIdx.x;
    int tm = tid >> 4, tn = tid & 15;
    float acc[4][4];
#pragma unroll
    for (int i = 0; i < 4; i++)
#pragma unroll
        for (int j = 0; j < 4; j++) acc[i][j] = 0.f;

    int lr = tid >> 2;
    int lk = (tid & 3) * 4;
    long abase;
    {
        int gm = m0 + lr;
        abase = gidx ? (long)gidx[gm] * lda : (long)gm * lda;
    }
    int gn = n0 + lr;
    long bbase = (long)gn * ldb;
    bool bvalid = gn < N;

    for (int k0 = 0; k0 < K; k0 += 16) {
#pragma unroll
        for (int i = 0; i < 4; i++) {
            int k = k0 + lk + i;
            As[lk + i][lr] = (k < K) ? A[abase + k] : 0.f;
            Bs[lk + i][lr] = (bvalid && k < K) ? Bw[bbase + k] : 0.f;
        }
        __syncthreads();
#pragma unroll
        for (int kk = 0; kk < 16; kk++) {
            float a[4], b[4];
#pragma unroll
            for (int i = 0; i < 4; i++) a[i] = As[kk][tm * 4 + i];
#pragma unroll
            for (int j = 0; j < 4; j++) b[j] = Bs[kk][tn * 4 + j];
#pragma unroll
            for (int i = 0; i < 4; i++)
#pragma unroll
                for (int j = 0; j < 4; j++) acc[i][j] += a[i] * b[j];
        }
        __syncthreads();
    }
#pragma unroll
    for (int i = 0; i < 4; i++) {
        int m = m0 + tm * 4 + i;
#pragma unroll
        for (int j = 0; j < 4; j++) {
            int n = n0 + tn * 4 + j;
            if (n < N) {
                float v = acc[i][j] + bias[n];
                if (act == 1) v = tanhf(v);
                C[(long)m * ldc + n] = v;
            }
        }
    }
}

// ============ persistent encoder recurrence (fwd+bwd), cooperative ==========
// 256 wgs x 256 thr; wg = dir*128 + d owns h-dims j0=d*4 .. +3 (16 gate rows).
// Whh slice register-resident. LDS: 32KB h stage + 1KB gbuf.
__global__ __launch_bounds__(256, 1)
void enc_recur(const float* __restrict__ xg_f, const float* __restrict__ xg_b,
               const float* __restrict__ Wf, const float* __restrict__ Wb,
               float* __restrict__ hglob, float* __restrict__ enc_out,
               float* __restrict__ encc) {
    cg::grid_group grid = cg::this_grid();
    __shared__ float hs[HH * 16];       // 32 KB
    __shared__ float gbuf[BB * 17];
    int wg  = blockIdx.x;
    int dir = wg >> 7;
    int j0  = (wg & 127) * 4;
    int tid = threadIdx.x;
    int ks   = tid & 31;
    int tile = tid >> 5;
    int bh   = tile >> 2;
    int nql  = (tile & 3) << 2;
    int gate = nql >> 2;
    int sw   = (ks >> 2) & 3;
    const float* W  = dir ? Wb : Wf;    // [2048][512]
    const float* xg = dir ? xg_b : xg_f;

    float wreg[4][16];
#pragma unroll
    for (int jn = 0; jn < 4; jn++) {
        const float* wrow = W + (long)(gate * HH + j0 + jn) * HH;
#pragma unroll
        for (int j = 0; j < 16; j++) wreg[jn][j] = wrow[ks + 32 * j];
    }

    int ub = tid & 15, ujj = tid >> 4;
    float creg = 0.f;
    float4* hsv = (float4*)hs;

    for (int t = 0; t < LKK; t++) {
        if (t == 0) {
            for (int i = tid; i < HH * 16; i += 256) hs[i] = 0.f;
        } else {
            const float4* hg4 = (const float4*)(hglob + (long)((dir << 1) | (t & 1)) * (HH * 16));
#pragma unroll
            for (int u = 0; u < 8; u++) {
                int i4 = tid + u * 256;
                int k = i4 >> 2, g = i4 & 3;
                hsv[k * 4 + (g ^ ((k >> 2) & 3))] = hg4[i4];
            }
        }
        float4 xr[8];
        if (ks == 0) {
#pragma unroll
            for (int i = 0; i < 8; i++) {
                const float* xp = xg + (long)((bh * 8 + i) * LKK + t) * G4 + gate * HH + j0;
                xr[i] = *(const float4*)xp;
            }
        }
        __syncthreads();

        float acc[8][4];
#pragma unroll
        for (int i = 0; i < 8; i++)
#pragma unroll
            for (int jn = 0; jn < 4; jn++) acc[i][jn] = 0.f;
#pragma unroll
        for (int j = 0; j < 16; j++) {
            int k = ks + 32 * j;
            float4 h0 = hsv[k * 4 + ((bh * 2 + 0) ^ sw)];
            float4 h1 = hsv[k * 4 + ((bh * 2 + 1) ^ sw)];
#pragma unroll
            for (int jn = 0; jn < 4; jn++) {
                float w = wreg[jn][j];
                acc[0][jn] += h0.x * w; acc[1][jn] += h0.y * w;
                acc[2][jn] += h0.z * w; acc[3][jn] += h0.w * w;
                acc[4][jn] += h1.x * w; acc[5][jn] += h1.y * w;
                acc[6][jn] += h1.z * w; acc[7][jn] += h1.w * w;
            }
        }
#pragma unroll
        for (int i = 0; i < 8; i++)
#pragma unroll
            for (int jn = 0; jn < 4; jn++) {
                float v = acc[i][jn];
                v += __shfl_xor(v, 1, 64);  v += __shfl_xor(v, 2, 64);
                v += __shfl_xor(v, 4, 64);  v += __shfl_xor(v, 8, 64);
                v += __shfl_xor(v, 16, 64);
                acc[i][jn] = v;
            }
        if (ks == 0) {
#pragma unroll
            for (int i = 0; i < 8; i++)
#pragma unroll
                for (int jn = 0; jn < 4; jn++)
                    gbuf[(bh * 8 + i) * 17 + nql + jn] = acc[i][jn] + ((const float*)&xr[i])[jn];
        }
        __syncthreads();

        if (tid < 64) {
            int j = j0 + ujj;
            float gi = gbuf[ub * 17 + 0  + ujj];
            float gf = gbuf[ub * 17 + 4  + ujj];
            float gg = gbuf[ub * 17 + 8  + ujj];
            float go = gbuf[ub * 17 + 12 + ujj];
            float cv = sigmoidf_(gf) * creg + sigmoidf_(gi) * tanhf(gg);
            creg = cv;
            float hv = sigmoidf_(go) * tanhf(cv);
            hglob[(long)((dir << 1) | ((t + 1) & 1)) * (HH * 16) + j * 16 + ub] = hv;
            int kpos = dir ? (LKK - 1 - t) : t;
            enc_out[(long)(ub * LKK + kpos) * H2 + dir * HH + j] = hv;
            if (t == LKK - 1) encc[(dir * BB + ub) * HH + j] = creg;
        }
        __threadfence();
        if (t < LKK - 1) { grid.sync(); __threadfence(); }
    }
}

// ============ persistent decoder recurrence, cooperative ====================
// 256 wgs; wg owns j0=wg*4 .. +3 of 1024 h-dims. h staged in TWO 512-dim
// halves (32KB LDS, below the 64KB/wg edge that likely killed round 2).
__global__ __launch_bounds__(256, 1)
void dec_recur(const float* __restrict__ xg_d, const float* __restrict__ Wd,
               const float* __restrict__ enc_out, const float* __restrict__ encc,
               float* __restrict__ hglob, float* __restrict__ Qout) {
    cg::grid_group grid = cg::this_grid();
    __shared__ float hs[HH * 16];       // 32 KB (one half of h)
    __shared__ float gbuf[BB * 17];
    int wg  = blockIdx.x;
    int j0  = wg * 4;
    int tid = threadIdx.x;
    int ks   = tid & 31;
    int tile = tid >> 5;
    int bh   = tile >> 2;
    int nql  = (tile & 3) << 2;
    int gate = nql >> 2;
    int sw   = (ks >> 2) & 3;

    float wreg[4][32];
#pragma unroll
    for (int jn = 0; jn < 4; jn++) {
        const float* wrow = Wd + (long)(gate * H2 + j0 + jn) * H2;
#pragma unroll
        for (int j = 0; j < 32; j++) wreg[jn][j] = wrow[ks + 32 * j];
    }

    int ub = tid & 15, ujj = tid >> 4;
    float creg = 0.f;
    if (tid < 64) {
        int j = j0 + ujj;
        creg = ((j & 1) == 0) ? encc[ub * HH + (j >> 1)]
                              : encc[(BB + ub) * HH + (j >> 1)];
    }
    float4* hsv = (float4*)hs;

    for (int t = 0; t < LQQ; t++) {
        float4 xr[8];
        if (ks == 0) {
#pragma unroll
            for (int i = 0; i < 8; i++) {
                const float* xp = xg_d + (long)((bh * 8 + i) * LQQ + t) * G8 + gate * H2 + j0;
                xr[i] = *(const float4*)xp;
            }
        }
        float acc[8][4];
#pragma unroll
        for (int i = 0; i < 8; i++)
#pragma unroll
            for (int jn = 0; jn < 4; jn++) acc[i][jn] = 0.f;

#pragma unroll
        for (int half = 0; half < 2; half++) {
            // ---- stage this 512-dim half of h into LDS ----
            if (t == 0) {
                for (int e = tid; e < HH * 16; e += 256) {
                    int kl = e >> 4, b = e & 15;
                    int k = half * HH + kl;   // global h-dim, interleaved layout
                    float hv = ((k & 1) == 0)
                        ? enc_out[(long)(b * LKK + (LKK - 1)) * H2 + (k >> 1)]
                        : enc_out[(long)(b * LKK) * H2 + HH + (k >> 1)];
                    hs[(kl << 4) + ((((b >> 2) ^ ((kl >> 2) & 3))) << 2) + (b & 3)] = hv;
                }
            } else {
                const float4* hg4 = (const float4*)(hglob + (long)(t & 1) * (H2 * 16))
                                    + (long)half * (HH * 4);
#pragma unroll
                for (int u = 0; u < 8; u++) {
                    int i4 = tid + u * 256;
                    int kl = i4 >> 2, g = i4 & 3;
                    hsv[kl * 4 + (g ^ ((kl >> 2) & 3))] = hg4[i4];
                }
            }
            __syncthreads();
            // ---- accumulate this half's K range ----
#pragma unroll
            for (int jj2 = 0; jj2 < 16; jj2++) {
                int j = half * 16 + jj2;
                int kl = ks + 32 * jj2;
                float4 h0 = hsv[kl * 4 + ((bh * 2 + 0) ^ sw)];
                float4 h1 = hsv[kl * 4 + ((bh * 2 + 1) ^ sw)];
#pragma unroll
                for (int jn = 0; jn < 4; jn++) {
                    float w = wreg[jn][j];
                    acc[0][jn] += h0.x * w; acc[1][jn] += h0.y * w;
                    acc[2][jn] += h0.z * w; acc[3][jn] += h0.w * w;
                    acc[4][jn] += h1.x * w; acc[5][jn] += h1.y * w;
                    acc[6][jn] += h1.z * w; acc[7][jn] += h1.w * w;
                }
            }
            __syncthreads();   // reads done before next half overwrites hs
        }

#pragma unroll
        for (int i = 0; i < 8; i++)
#pragma unroll
            for (int jn = 0; jn < 4; jn++) {
                float v = acc[i][jn];
                v += __shfl_xor(v, 1, 64);  v += __shfl_xor(v, 2, 64);
                v += __shfl_xor(v, 4, 64);  v += __shfl_xor(v, 8, 64);
                v += __shfl_xor(v, 16, 64);
                acc[i][jn] = v;
            }
        if (ks == 0) {
#pragma unroll
            for (int i = 0; i < 8; i++)
#pragma unroll
                for (int jn = 0; jn < 4; jn++)
                    gbuf[(bh * 8 + i) * 17 + nql + jn] = acc[i][jn] + ((const float*)&xr[i])[jn];
        }
        __syncthreads();

        if (tid < 64) {
            int j = j0 + ujj;
            float gi = gbuf[ub * 17 + 0  + ujj];
            float gf = gbuf[ub * 17 + 4  + ujj];
            float gg = gbuf[ub * 17 + 8  + ujj];
            float go = gbuf[ub * 17 + 12 + ujj];
            float cv = sigmoidf_(gf) * creg + sigmoidf_(gi) * tanhf(gg);
            creg = cv;
            float hv = sigmoidf_(go) * tanhf(cv);
            hglob[(long)((t + 1) & 1) * (H2 * 16) + j * 16 + ub] = hv;
            Qout[(long)(ub * LQQ + t) * H2 + j] = hv;
        }
        __threadfence();
        if (t < LQQ - 1) { grid.sync(); __threadfence(); }
    }
}

// ============ fallback per-step kernels (round-1 verbatim, known-good) ======
__global__ __launch_bounds__(256)
void enc_step_kernel(const float* __restrict__ xg_f, const float* __restrict__ xg_b,
                     const float* __restrict__ wt_f, const float* __restrict__ wt_b,
                     const float* __restrict__ g_prev, float* __restrict__ g_cur,
                     const float* __restrict__ c_prev, float* __restrict__ c_cur,
                     float* __restrict__ enc_out, int t) {
    int dir = blockIdx.x >> 5;
    int chunk = blockIdx.x & 31;
    int tid = threadIdx.x;
    __shared__ float hsl[BB][HH];

    for (int e = tid; e < BB * HH; e += 256) {
        int b = e >> 9, j = e & (HH - 1);
        float hv, cv;
        if (t == 0) { hv = 0.f; cv = 0.f; }
        else {
            const float* gp = g_prev + (long)(dir * BB + b) * G4;
            float gi = gp[j], gf = gp[j + HH], gg = gp[j + 2 * HH], go = gp[j + 3 * HH];
            float cp = c_prev[(dir * BB + b) * HH + j];
            cv = sigmoidf_(gf) * cp + sigmoidf_(gi) * tanhf(gg);
            hv = sigmoidf_(go) * tanhf(cv);
        }
        hsl[b][j] = hv;
        if (chunk == 0) {
            c_cur[(dir * BB + b) * HH + j] = cv;
            if (t >= 1) {
                int s = t - 1;
                int kpos = (dir == 0) ? s : (LKK - 1 - s);
                enc_out[(long)(b * LKK + kpos) * H2 + dir * HH + j] = hv;
            }
        }
    }
    if (t == LKK) return;
    __syncthreads();

    const float* wt = dir ? wt_b : wt_f;
    const float* xg = dir ? xg_b : xg_f;
    int n = chunk * 64 + (tid & 63);
    int rb = (tid >> 6) * 4;
    float a0 = 0.f, a1 = 0.f, a2 = 0.f, a3 = 0.f;
#pragma unroll 8
    for (int k = 0; k < HH; k++) {
        float w = wt[(long)k * G4 + n];
        a0 += hsl[rb + 0][k] * w;
        a1 += hsl[rb + 1][k] * w;
        a2 += hsl[rb + 2][k] * w;
        a3 += hsl[rb + 3][k] * w;
    }
    g_cur[(long)(dir * BB + rb + 0) * G4 + n] = xg[(long)((rb + 0) * LKK + t) * G4 + n] + a0;
    g_cur[(long)(dir * BB + rb + 1) * G4 + n] = xg[(long)((rb + 1) * LKK + t) * G4 + n] + a1;
    g_cur[(long)(dir * BB + rb + 2) * G4 + n] = xg[(long)((rb + 2) * LKK + t) * G4 + n] + a2;
    g_cur[(long)(dir * BB + rb + 3) * G4 + n] = xg[(long)((rb + 3) * LKK + t) * G4 + n] + a3;
}

__global__ __launch_bounds__(256)
void dec_step_kernel(const float* __restrict__ xg_d, const float* __restrict__ wt_d,
                     const float* __restrict__ g_prev, float* __restrict__ g_cur,
                     const float* __restrict__ c_prev, float* __restrict__ c_cur,
                     const float* __restrict__ enc_out, const float* __restrict__ enc_c_fin,
                     float* __restrict__ Qout, int t) {
    int rh = blockIdx.x >> 6;
    int chunk = blockIdx.x & 63;
    int tid = threadIdx.x;
    int b0 = rh * 8;
    __shared__ float hsl[8][H2];

    for (int e = tid; e < 8 * H2; e += 256) {
        int br = e >> 10, j = e & (H2 - 1);
        int b = b0 + br;
        float hv, cv;
        if (t == 0) {
            int jj = j >> 1;
            if ((j & 1) == 0) {
                hv = enc_out[(long)(b * LKK + (LKK - 1)) * H2 + jj];
                cv = enc_c_fin[(0 * BB + b) * HH + jj];
            } else {
                hv = enc_out[(long)(b * LKK + 0) * H2 + HH + jj];
                cv = enc_c_fin[(1 * BB + b) * HH + jj];
            }
        } else {
            const float* gp = g_prev + (long)b * G8;
            float gi = gp[j], gf = gp[j + H2], gg = gp[j + 2 * H2], go = gp[j + 3 * H2];
            float cp = c_prev[b * H2 + j];
            cv = sigmoidf_(gf) * cp + sigmoidf_(gi) * tanhf(gg);
            hv = sigmoidf_(go) * tanhf(cv);
        }
        hsl[br][j] = hv;
        if (chunk == 0) {
            c_cur[b * H2 + j] = cv;
            if (t >= 1) Qout[(long)(b * LQQ + (t - 1)) * H2 + j] = hv;
        }
    }
    if (t == LQQ) return;
    __syncthreads();

    int n = chunk * 64 + (tid & 63);
    int r2 = (tid >> 6) * 2;
    float a0 = 0.f, a1 = 0.f;
#pragma unroll 8
    for (int k = 0; k < H2; k++) {
        float w = wt_d[(long)k * G8 + n];
        a0 += hsl[r2 + 0][k] * w;
        a1 += hsl[r2 + 1][k] * w;
    }
    int b = b0 + r2;
    g_cur[(long)b * G8 + n]       = xg_d[(long)(b * LQQ + t) * G8 + n] + a0;
    g_cur[(long)(b + 1) * G8 + n] = xg_d[(long)((b + 1) * LQQ + t) * G8 + n] + a1;
}

// ---------------- attention + concat[ctx, Q] ---------------------------------
__global__ __launch_bounds__(256)
void attention_kernel(const float* __restrict__ Qm, const float* __restrict__ Km,
                      const float* __restrict__ Vm, const int* __restrict__ source,
                      float* __restrict__ concatBuf) {
    int b = blockIdx.x >> 6;
    int q = blockIdx.x & 63;
    int tid = threadIdx.x;
    __shared__ float qrow[H2];
    __shared__ float part[LKK][4];
    __shared__ float aw[LKK];

    for (int i = tid; i < H2; i += 256) qrow[i] = Qm[(long)(b * LQQ + q) * H2 + i];
    __syncthreads();

    int k = tid >> 2, p = tid & 3;
    {
        const float* krow = Km + (long)(b * LKK + k) * H2 + p * 256;
        const float* qp = qrow + p * 256;
        float s = 0.f;
#pragma unroll 4
        for (int i = 0; i < 256; i++) s += qp[i] * krow[i];
        part[k][p] = s;
    }
    __syncthreads();
    if (tid < 64) {
        float sc = part[tid][0] + part[tid][1] + part[tid][2] + part[tid][3];
        bool masked = (source[b * LKK + tid] == 0);
        float m = masked ? -INFINITY : sc;
#pragma unroll
        for (int o = 32; o >= 1; o >>= 1) m = fmaxf(m, __shfl_xor(m, o, 64));
        float e = masked ? 0.f : expf(sc - m);
        float sum = e;
#pragma unroll
        for (int o = 32; o >= 1; o >>= 1) sum += __shfl_xor(sum, o, 64);
        aw[tid] = e / sum;
    }
    __syncthreads();

    for (int c = tid; c < H2; c += 256) {
        float acc = 0.f;
#pragma unroll 8
        for (int kk = 0; kk < LKK; kk++) acc += aw[kk] * Vm[(long)(b * LKK + kk) * H2 + c];
        long row = (long)(b * LQQ + q) * (2 * H2);
        concatBuf[row + c] = acc;
        concatBuf[row + H2 + c] = qrow[c];
    }
}

// ---------------- host launcher ----------------------------------------------
extern "C" void kernel_launch(void* const* d_in, const int* in_sizes, int n_in,
                              void* d_out, int out_size, void* d_ws, size_t ws_size,
                              hipStream_t stream) {
    const int*   src       = (const int*)  d_in[0];
    const int*   prev      = (const int*)  d_in[1];
    const float* emb       = (const float*)d_in[2];
    const float* enc_f_Wih = (const float*)d_in[3];
    const float* enc_f_Whh = (const float*)d_in[4];
    const float* enc_f_b   = (const float*)d_in[5];
    const float* enc_b_Wih = (const float*)d_in[6];
    const float* enc_b_Whh = (const float*)d_in[7];
    const float* enc_b_b   = (const float*)d_in[8];
    const float* dec_Wih   = (const float*)d_in[9];
    const float* dec_Whh   = (const float*)d_in[10];
    const float* dec_b     = (const float*)d_in[11];
    const float* k_W  = (const float*)d_in[12];
    const float* k_b  = (const float*)d_in[13];
    const float* v_W  = (const float*)d_in[14];
    const float* v_b  = (const float*)d_in[15];
    const float* fc1_W = (const float*)d_in[16];
    const float* fc1_b = (const float*)d_in[17];
    const float* fc2_W = (const float*)d_in[18];
    const float* fc2_b = (const float*)d_in[19];
    float* out = (float*)d_out;

    // workspace layout (floats) — union of coop + fallback paths (~90 MB)
    float* p = (float*)d_ws;
    float* xg_f    = p; p += (long)BB * LKK * G4;
    float* xg_b    = p; p += (long)BB * LKK * G4;
    float* xg_d    = p; p += (long)BB * LQQ * G8;
    float* enc_out = p; p += (long)BB * LKK * H2;
    float* encc    = p; p += 2L * BB * HH;
    float* hg_enc  = p; p += 2L * 2 * HH * 16;
    float* hg_dec  = p; p += 2L * H2 * 16;
    float* Qbuf    = p; p += (long)BB * LQQ * H2;
    float* Kbuf    = p; p += (long)BB * LKK * H2;
    float* Vbuf    = p; p += (long)BB * LKK * H2;
    float* concatB = p; p += (long)BB * LQQ * 2 * H2;
    float* fc1out  = p; p += (long)BB * LQQ * H2;
    float* wt_f    = p; p += (long)HH * G4;      // fallback only
    float* wt_b    = p; p += (long)HH * G4;
    float* wt_d    = p; p += (long)H2 * G8;
    float* enc_g   = p; p += 2L * 2 * BB * G4;
    float* enc_c   = p; p += 2L * 2 * BB * HH;
    float* dec_g   = p; p += 2L * BB * G8;
    float* dec_c   = p; p += 2L * BB * H2;
    int*   rev     = (int*)p; p += (BB * LKK);

    // 1) reversed source indices
    rev_idx_kernel<<<4, 256, 0, stream>>>(src, rev);

    // 2) xg precomputes (gathered-embedding GEMMs)
    gemm_nt_kernel<<<dim3(16, G4 / 64), 256, 0, stream>>>(emb, src, DD, enc_f_Wih, DD,
                                                          enc_f_b, xg_f, G4, G4, DD, 0);
    gemm_nt_kernel<<<dim3(16, G4 / 64), 256, 0, stream>>>(emb, rev, DD, enc_b_Wih, DD,
                                                          enc_b_b, xg_b, G4, G4, DD, 0);
    gemm_nt_kernel<<<dim3(16, G8 / 64), 256, 0, stream>>>(emb, prev, DD, dec_Wih, DD,
                                                          dec_b, xg_d, G8, G8, DD, 0);

    // 3) encoder recurrence: cooperative persistent kernel, else per-step fallback
    const float* cfin = encc;
    {
        void* args[7];
        args[0] = (void*)&xg_f;      args[1] = (void*)&xg_b;
        args[2] = (void*)&enc_f_Whh; args[3] = (void*)&enc_b_Whh;
        args[4] = (void*)&hg_enc;    args[5] = (void*)&enc_out;
        args[6] = (void*)&encc;
        hipError_t ce = hipLaunchCooperativeKernel(enc_recur, dim3(256), dim3(256),
                                                   args, 0, stream);
        if (ce != hipSuccess) {
            transpose_kernel<<<(G4 * HH + 255) / 256, 256, 0, stream>>>(enc_f_Whh, wt_f, G4, HH);
            transpose_kernel<<<(G4 * HH + 255) / 256, 256, 0, stream>>>(enc_b_Whh, wt_b, G4, HH);
            for (int t = 0; t <= LKK; t++) {
                const float* gp = enc_g + (long)((t + 1) & 1) * 2 * BB * G4;
                float*       gc = enc_g + (long)(t & 1) * 2 * BB * G4;
                const float* cp = enc_c + (long)((t + 1) & 1) * 2 * BB * HH;
                float*       cc = enc_c + (long)(t & 1) * 2 * BB * HH;
                enc_step_kernel<<<64, 256, 0, stream>>>(xg_f, xg_b, wt_f, wt_b, gp, gc,
                                                        cp, cc, enc_out, t);
            }
            cfin = enc_c;   // t=64 wrote ping-pong slot 0 (same layout as encc)
        }
    }

    // 4) K/V projections
    gemm_nt_kernel<<<dim3(16, 16), 256, 0, stream>>>(enc_out, nullptr, H2, k_W, H2,
                                                     k_b, Kbuf, H2, H2, H2, 0);
    gemm_nt_kernel<<<dim3(16, 16), 256, 0, stream>>>(enc_out, nullptr, H2, v_W, H2,
                                                     v_b, Vbuf, H2, H2, H2, 0);

    // 5) decoder recurrence: cooperative persistent kernel, else per-step fallback
    {
        void* args[6];
        args[0] = (void*)&xg_d;    args[1] = (void*)&dec_Whh;
        args[2] = (void*)&enc_out; args[3] = (void*)&cfin;
        args[4] = (void*)&hg_dec;  args[5] = (void*)&Qbuf;
        hipError_t cd = hipLaunchCooperativeKernel(dec_recur, dim3(256), dim3(256),
                                                   args, 0, stream);
        if (cd != hipSuccess) {
            transpose_kernel<<<(G8 * H2 + 255) / 256, 256, 0, stream>>>(dec_Whh, wt_d, G8, H2);
            for (int t = 0; t <= LQQ; t++) {
                const float* gp = dec_g + (long)((t + 1) & 1) * BB * G8;
                float*       gc = dec_g + (long)(t & 1) * BB * G8;
                const float* cp = dec_c + (long)((t + 1) & 1) * BB * H2;
                float*       cc = dec_c + (long)(t & 1) * BB * H2;
                dec_step_kernel<<<128, 256, 0, stream>>>(xg_d, wt_d, gp, gc, cp, cc,
                                                         enc_out, cfin, Qbuf, t);
            }
        }
    }

    // 6) attention -> concat[ctx, Q]
    attention_kernel<<<BB * LQQ, 256, 0, stream>>>(Qbuf, Kbuf, Vbuf, src, concatB);

    // 7) fc1 with tanh
    gemm_nt_kernel<<<dim3(16, 16), 256, 0, stream>>>(concatB, nullptr, 2 * H2, fc1_W, 2 * H2,
                                                     fc1_b, fc1out, H2, H2, 2 * H2, 1);

    // 8) fc2 -> output [1024, 10000]
    gemm_nt_kernel<<<dim3(16, (VV + 63) / 64), 256, 0, stream>>>(fc1out, nullptr, H2, fc2_W, H2,
                                                                 fc2_b, out, VV, VV, H2, 0);
}

// Round 4
// 2836.323 us; speedup vs baseline: 3.5549x; 3.5549x over previous
//
#include <hip/hip_runtime.h>
#include <cmath>

// Problem constants
#define BB   16
#define LKK  64
#define LQQ  64
#define DD   300
#define HH   512
#define H2   1024
#define G4   2048
#define G8   4096
#define VV   10000

__device__ __forceinline__ float sigmoidf_(float x) { return 1.f / (1.f + expf(-x)); }

// ---- agent-scope (cross-XCD coherent) scalar access: sc0|sc1, no cache ops ----
__device__ __forceinline__ float ld_sc(const float* p) {
    return __hip_atomic_load(p, __ATOMIC_RELAXED, __HIP_MEMORY_SCOPE_AGENT);
}
__device__ __forceinline__ void st_sc(float* p, float v) {
    __hip_atomic_store(p, v, __ATOMIC_RELAXED, __HIP_MEMORY_SCOPE_AGENT);
}

// ---- lean grid barrier: monotone counter, no wbL2/inv. All shared data must
// have been written with st_sc (write-through); vmcnt(0) => globally visible.
__device__ __forceinline__ void gbar(unsigned* cnt, unsigned target) {
    asm volatile("s_waitcnt vmcnt(0)" ::: "memory");
    __syncthreads();
    if (threadIdx.x == 0) {
        __hip_atomic_fetch_add(cnt, 1u, __ATOMIC_RELAXED, __HIP_MEMORY_SCOPE_AGENT);
        while (__hip_atomic_load(cnt, __ATOMIC_RELAXED, __HIP_MEMORY_SCOPE_AGENT) < target)
            __builtin_amdgcn_s_sleep(2);
    }
    __syncthreads();
}

// ---------------- reverse source indices + barrier-counter init --------------
__global__ void rev_idx_kernel(const int* __restrict__ src, int* __restrict__ rev,
                               unsigned* __restrict__ bars) {
    int tid = blockIdx.x * blockDim.x + threadIdx.x;
    if (tid < 2) bars[tid] = 0u;
    if (tid < BB * LKK) {
        int b = tid / LKK, t = tid % LKK;
        rev[tid] = src[b * LKK + (LKK - 1 - t)];
    }
}

// ---------------- transpose (fallback path): out[k*N+n] = in[n*K+k] ----------
__global__ void transpose_kernel(const float* __restrict__ in, float* __restrict__ out,
                                 int N, int K) {
    long tid = (long)blockIdx.x * blockDim.x + threadIdx.x;
    long total = (long)N * K;
    if (tid < total) {
        int n = (int)(tid % N);
        int k = (int)(tid / N);
        out[(long)k * N + n] = in[(long)n * K + k];
    }
}

// ---------------- generic NT GEMM: C[m,n] = sum_k A[m,k]*Bw[n,k] + bias[n] ----
__global__ __launch_bounds__(256)
void gemm_nt_kernel(const float* __restrict__ A, const int* __restrict__ gidx, int lda,
                    const float* __restrict__ Bw, int ldb,
                    const float* __restrict__ bias,
                    float* __restrict__ C, int ldc,
                    int N, int K, int act) {
    __shared__ float As[16][68];
    __shared__ float Bs[16][68];
    int m0 = blockIdx.x * 64;
    int n0 = blockIdx.y * 64;
    int tid = threadIdx.x;
    int tm = tid >> 4, tn = tid & 15;
    float acc[4][4];
#pragma unroll
    for (int i = 0; i < 4; i++)
#pragma unroll
        for (int j = 0; j < 4; j++) acc[i][j] = 0.f;

    int lr = tid >> 2;
    int lk = (tid & 3) * 4;
    long abase;
    {
        int gm = m0 + lr;
        abase = gidx ? (long)gidx[gm] * lda : (long)gm * lda;
    }
    int gn = n0 + lr;
    long bbase = (long)gn * ldb;
    bool bvalid = gn < N;

    for (int k0 = 0; k0 < K; k0 += 16) {
#pragma unroll
        for (int i = 0; i < 4; i++) {
            int k = k0 + lk + i;
            As[lk + i][lr] = (k < K) ? A[abase + k] : 0.f;
            Bs[lk + i][lr] = (bvalid && k < K) ? Bw[bbase + k] : 0.f;
        }
        __syncthreads();
#pragma unroll
        for (int kk = 0; kk < 16; kk++) {
            float a[4], b[4];
#pragma unroll
            for (int i = 0; i < 4; i++) a[i] = As[kk][tm * 4 + i];
#pragma unroll
            for (int j = 0; j < 4; j++) b[j] = Bs[kk][tn * 4 + j];
#pragma unroll
            for (int i = 0; i < 4; i++)
#pragma unroll
                for (int j = 0; j < 4; j++) acc[i][j] += a[i] * b[j];
        }
        __syncthreads();
    }
#pragma unroll
    for (int i = 0; i < 4; i++) {
        int m = m0 + tm * 4 + i;
#pragma unroll
        for (int j = 0; j < 4; j++) {
            int n = n0 + tn * 4 + j;
            if (n < N) {
                float v = acc[i][j] + bias[n];
                if (act == 1) v = tanhf(v);
                C[(long)m * ldc + n] = v;
            }
        }
    }
}

// ============ persistent encoder recurrence (fwd+bwd), cooperative ==========
// 256 wgs x 256 thr; wg = dir*128 + d owns h-dims j0=d*4 .. +3 (16 gate rows).
// Whh slice register-resident. h exchange via sc1 stores/loads + lean barrier.
__global__ __launch_bounds__(256, 1)
void enc_recur(const float* __restrict__ xg_f, const float* __restrict__ xg_b,
               const float* __restrict__ Wf, const float* __restrict__ Wb,
               float* __restrict__ hglob, float* __restrict__ enc_out,
               float* __restrict__ encc, unsigned* __restrict__ bar) {
    __shared__ float hs[HH * 16];       // 32 KB
    __shared__ float gbuf[BB * 17];
    int wg  = blockIdx.x;
    int dir = wg >> 7;
    int j0  = (wg & 127) * 4;
    int tid = threadIdx.x;
    int ks   = tid & 31;
    int tile = tid >> 5;
    int bh   = tile >> 2;
    int nql  = (tile & 3) << 2;
    int gate = nql >> 2;
    int sw   = (ks >> 2) & 3;
    const float* W  = dir ? Wb : Wf;    // [2048][512]
    const float* xg = dir ? xg_b : xg_f;

    float wreg[4][16];
#pragma unroll
    for (int jn = 0; jn < 4; jn++) {
        const float* wrow = W + (long)(gate * HH + j0 + jn) * HH;
#pragma unroll
        for (int j = 0; j < 16; j++) wreg[jn][j] = wrow[ks + 32 * j];
    }

    int ub = tid & 15, ujj = tid >> 4;
    float creg = 0.f;
    float4* hsv = (float4*)hs;

    for (int t = 0; t < LKK; t++) {
        if (t == 0) {
            for (int i = tid; i < HH * 16; i += 256) hs[i] = 0.f;
        } else {
            const float* hg = hglob + (long)((dir << 1) | (t & 1)) * (HH * 16);
            float vv[32];
#pragma unroll
            for (int u = 0; u < 32; u++) vv[u] = ld_sc(hg + tid + u * 256);
#pragma unroll
            for (int u = 0; u < 32; u++) {
                int e = tid + u * 256;
                int jj = e >> 4, b = e & 15;
                hs[(jj << 4) + ((((b >> 2) ^ ((jj >> 2) & 3))) << 2) + (b & 3)] = vv[u];
            }
        }
        float4 xr[8];
        if (ks == 0) {
#pragma unroll
            for (int i = 0; i < 8; i++) {
                const float* xp = xg + (long)((bh * 8 + i) * LKK + t) * G4 + gate * HH + j0;
                xr[i] = *(const float4*)xp;
            }
        }
        __syncthreads();

        float acc[8][4];
#pragma unroll
        for (int i = 0; i < 8; i++)
#pragma unroll
            for (int jn = 0; jn < 4; jn++) acc[i][jn] = 0.f;
#pragma unroll
        for (int j = 0; j < 16; j++) {
            int k = ks + 32 * j;
            float4 h0 = hsv[k * 4 + ((bh * 2 + 0) ^ sw)];
            float4 h1 = hsv[k * 4 + ((bh * 2 + 1) ^ sw)];
#pragma unroll
            for (int jn = 0; jn < 4; jn++) {
                float w = wreg[jn][j];
                acc[0][jn] += h0.x * w; acc[1][jn] += h0.y * w;
                acc[2][jn] += h0.z * w; acc[3][jn] += h0.w * w;
                acc[4][jn] += h1.x * w; acc[5][jn] += h1.y * w;
                acc[6][jn] += h1.z * w; acc[7][jn] += h1.w * w;
            }
        }
#pragma unroll
        for (int i = 0; i < 8; i++)
#pragma unroll
            for (int jn = 0; jn < 4; jn++) {
                float v = acc[i][jn];
                v += __shfl_xor(v, 1, 64);  v += __shfl_xor(v, 2, 64);
                v += __shfl_xor(v, 4, 64);  v += __shfl_xor(v, 8, 64);
                v += __shfl_xor(v, 16, 64);
                acc[i][jn] = v;
            }
        if (ks == 0) {
#pragma unroll
            for (int i = 0; i < 8; i++)
#pragma unroll
                for (int jn = 0; jn < 4; jn++)
                    gbuf[(bh * 8 + i) * 17 + nql + jn] = acc[i][jn] + ((const float*)&xr[i])[jn];
        }
        __syncthreads();

        if (tid < 64) {
            int j = j0 + ujj;
            float gi = gbuf[ub * 17 + 0  + ujj];
            float gf = gbuf[ub * 17 + 4  + ujj];
            float gg = gbuf[ub * 17 + 8  + ujj];
            float go = gbuf[ub * 17 + 12 + ujj];
            float cv = sigmoidf_(gf) * creg + sigmoidf_(gi) * tanhf(gg);
            creg = cv;
            float hv = sigmoidf_(go) * tanhf(cv);
            st_sc(&hglob[(long)((dir << 1) | ((t + 1) & 1)) * (HH * 16) + j * 16 + ub], hv);
            int kpos = dir ? (LKK - 1 - t) : t;
            enc_out[(long)(ub * LKK + kpos) * H2 + dir * HH + j] = hv;
            if (t == LKK - 1) encc[(dir * BB + ub) * HH + j] = creg;
        }
        if (t < LKK - 1) gbar(bar, 256u * (unsigned)(t + 1));
    }
}

// ============ persistent decoder recurrence, cooperative ====================
// 256 wgs; wg owns j0=wg*4 .. +3 of 1024 h-dims; h staged in two 512-dim halves.
__global__ __launch_bounds__(256, 1)
void dec_recur(const float* __restrict__ xg_d, const float* __restrict__ Wd,
               const float* __restrict__ enc_out, const float* __restrict__ encc,
               float* __restrict__ hglob, float* __restrict__ Qout,
               unsigned* __restrict__ bar) {
    __shared__ float hs[HH * 16];       // 32 KB (one half of h)
    __shared__ float gbuf[BB * 17];
    int wg  = blockIdx.x;
    int j0  = wg * 4;
    int tid = threadIdx.x;
    int ks   = tid & 31;
    int tile = tid >> 5;
    int bh   = tile >> 2;
    int nql  = (tile & 3) << 2;
    int gate = nql >> 2;
    int sw   = (ks >> 2) & 3;

    float wreg[4][32];
#pragma unroll
    for (int jn = 0; jn < 4; jn++) {
        const float* wrow = Wd + (long)(gate * H2 + j0 + jn) * H2;
#pragma unroll
        for (int j = 0; j < 32; j++) wreg[jn][j] = wrow[ks + 32 * j];
    }

    int ub = tid & 15, ujj = tid >> 4;
    float creg = 0.f;
    if (tid < 64) {
        int j = j0 + ujj;
        creg = ((j & 1) == 0) ? encc[ub * HH + (j >> 1)]
                              : encc[(BB + ub) * HH + (j >> 1)];
    }
    float4* hsv = (float4*)hs;

    for (int t = 0; t < LQQ; t++) {
        float4 xr[8];
        if (ks == 0) {
#pragma unroll
            for (int i = 0; i < 8; i++) {
                const float* xp = xg_d + (long)((bh * 8 + i) * LQQ + t) * G8 + gate * H2 + j0;
                xr[i] = *(const float4*)xp;
            }
        }
        float acc[8][4];
#pragma unroll
        for (int i = 0; i < 8; i++)
#pragma unroll
            for (int jn = 0; jn < 4; jn++) acc[i][jn] = 0.f;

#pragma unroll
        for (int half = 0; half < 2; half++) {
            // ---- stage this 512-dim half of h into LDS ----
            if (t == 0) {
                for (int e = tid; e < HH * 16; e += 256) {
                    int kl = e >> 4, b = e & 15;
                    int k = half * HH + kl;   // global h-dim, interleaved layout
                    float hv = ((k & 1) == 0)
                        ? enc_out[(long)(b * LKK + (LKK - 1)) * H2 + (k >> 1)]
                        : enc_out[(long)(b * LKK) * H2 + HH + (k >> 1)];
                    hs[(kl << 4) + ((((b >> 2) ^ ((kl >> 2) & 3))) << 2) + (b & 3)] = hv;
                }
            } else {
                const float* hg = hglob + (long)(t & 1) * (H2 * 16) + (long)half * (HH * 16);
                float vv[32];
#pragma unroll
                for (int u = 0; u < 32; u++) vv[u] = ld_sc(hg + tid + u * 256);
#pragma unroll
                for (int u = 0; u < 32; u++) {
                    int e = tid + u * 256;
                    int kl = e >> 4, b = e & 15;
                    hs[(kl << 4) + ((((b >> 2) ^ ((kl >> 2) & 3))) << 2) + (b & 3)] = vv[u];
                }
            }
            __syncthreads();
            // ---- accumulate this half's K range ----
#pragma unroll
            for (int jj2 = 0; jj2 < 16; jj2++) {
                int j = half * 16 + jj2;
                int kl = ks + 32 * jj2;
                float4 h0 = hsv[kl * 4 + ((bh * 2 + 0) ^ sw)];
                float4 h1 = hsv[kl * 4 + ((bh * 2 + 1) ^ sw)];
#pragma unroll
                for (int jn = 0; jn < 4; jn++) {
                    float w = wreg[jn][j];
                    acc[0][jn] += h0.x * w; acc[1][jn] += h0.y * w;
                    acc[2][jn] += h0.z * w; acc[3][jn] += h0.w * w;
                    acc[4][jn] += h1.x * w; acc[5][jn] += h1.y * w;
                    acc[6][jn] += h1.z * w; acc[7][jn] += h1.w * w;
                }
            }
            __syncthreads();   // reads done before next half overwrites hs
        }

#pragma unroll
        for (int i = 0; i < 8; i++)
#pragma unroll
            for (int jn = 0; jn < 4; jn++) {
                float v = acc[i][jn];
                v += __shfl_xor(v, 1, 64);  v += __shfl_xor(v, 2, 64);
                v += __shfl_xor(v, 4, 64);  v += __shfl_xor(v, 8, 64);
                v += __shfl_xor(v, 16, 64);
                acc[i][jn] = v;
            }
        if (ks == 0) {
#pragma unroll
            for (int i = 0; i < 8; i++)
#pragma unroll
                for (int jn = 0; jn < 4; jn++)
                    gbuf[(bh * 8 + i) * 17 + nql + jn] = acc[i][jn] + ((const float*)&xr[i])[jn];
        }
        __syncthreads();

        if (tid < 64) {
            int j = j0 + ujj;
            float gi = gbuf[ub * 17 + 0  + ujj];
            float gf = gbuf[ub * 17 + 4  + ujj];
            float gg = gbuf[ub * 17 + 8  + ujj];
            float go = gbuf[ub * 17 + 12 + ujj];
            float cv = sigmoidf_(gf) * creg + sigmoidf_(gi) * tanhf(gg);
            creg = cv;
            float hv = sigmoidf_(go) * tanhf(cv);
            st_sc(&hglob[(long)((t + 1) & 1) * (H2 * 16) + j * 16 + ub], hv);
            Qout[(long)(ub * LQQ + t) * H2 + j] = hv;
        }
        if (t < LQQ - 1) gbar(bar, 256u * (unsigned)(t + 1));
    }
}

// ============ fallback per-step kernels (round-1 verbatim, known-good) ======
__global__ __launch_bounds__(256)
void enc_step_kernel(const float* __restrict__ xg_f, const float* __restrict__ xg_b,
                     const float* __restrict__ wt_f, const float* __restrict__ wt_b,
                     const float* __restrict__ g_prev, float* __restrict__ g_cur,
                     const float* __restrict__ c_prev, float* __restrict__ c_cur,
                     float* __restrict__ enc_out, int t) {
    int dir = blockIdx.x >> 5;
    int chunk = blockIdx.x & 31;
    int tid = threadIdx.x;
    __shared__ float hsl[BB][HH];

    for (int e = tid; e < BB * HH; e += 256) {
        int b = e >> 9, j = e & (HH - 1);
        float hv, cv;
        if (t == 0) { hv = 0.f; cv = 0.f; }
        else {
            const float* gp = g_prev + (long)(dir * BB + b) * G4;
            float gi = gp[j], gf = gp[j + HH], gg = gp[j + 2 * HH], go = gp[j + 3 * HH];
            float cp = c_prev[(dir * BB + b) * HH + j];
            cv = sigmoidf_(gf) * cp + sigmoidf_(gi) * tanhf(gg);
            hv = sigmoidf_(go) * tanhf(cv);
        }
        hsl[b][j] = hv;
        if (chunk == 0) {
            c_cur[(dir * BB + b) * HH + j] = cv;
            if (t >= 1) {
                int s = t - 1;
                int kpos = (dir == 0) ? s : (LKK - 1 - s);
                enc_out[(long)(b * LKK + kpos) * H2 + dir * HH + j] = hv;
            }
        }
    }
    if (t == LKK) return;
    __syncthreads();

    const float* wt = dir ? wt_b : wt_f;
    const float* xg = dir ? xg_b : xg_f;
    int n = chunk * 64 + (tid & 63);
    int rb = (tid >> 6) * 4;
    float a0 = 0.f, a1 = 0.f, a2 = 0.f, a3 = 0.f;
#pragma unroll 8
    for (int k = 0; k < HH; k++) {
        float w = wt[(long)k * G4 + n];
        a0 += hsl[rb + 0][k] * w;
        a1 += hsl[rb + 1][k] * w;
        a2 += hsl[rb + 2][k] * w;
        a3 += hsl[rb + 3][k] * w;
    }
    g_cur[(long)(dir * BB + rb + 0) * G4 + n] = xg[(long)((rb + 0) * LKK + t) * G4 + n] + a0;
    g_cur[(long)(dir * BB + rb + 1) * G4 + n] = xg[(long)((rb + 1) * LKK + t) * G4 + n] + a1;
    g_cur[(long)(dir * BB + rb + 2) * G4 + n] = xg[(long)((rb + 2) * LKK + t) * G4 + n] + a2;
    g_cur[(long)(dir * BB + rb + 3) * G4 + n] = xg[(long)((rb + 3) * LKK + t) * G4 + n] + a3;
}

__global__ __launch_bounds__(256)
void dec_step_kernel(const float* __restrict__ xg_d, const float* __restrict__ wt_d,
                     const float* __restrict__ g_prev, float* __restrict__ g_cur,
                     const float* __restrict__ c_prev, float* __restrict__ c_cur,
                     const float* __restrict__ enc_out, const float* __restrict__ enc_c_fin,
                     float* __restrict__ Qout, int t) {
    int rh = blockIdx.x >> 6;
    int chunk = blockIdx.x & 63;
    int tid = threadIdx.x;
    int b0 = rh * 8;
    __shared__ float hsl[8][H2];

    for (int e = tid; e < 8 * H2; e += 256) {
        int br = e >> 10, j = e & (H2 - 1);
        int b = b0 + br;
        float hv, cv;
        if (t == 0) {
            int jj = j >> 1;
            if ((j & 1) == 0) {
                hv = enc_out[(long)(b * LKK + (LKK - 1)) * H2 + jj];
                cv = enc_c_fin[(0 * BB + b) * HH + jj];
            } else {
                hv = enc_out[(long)(b * LKK + 0) * H2 + HH + jj];
                cv = enc_c_fin[(1 * BB + b) * HH + jj];
            }
        } else {
            const float* gp = g_prev + (long)b * G8;
            float gi = gp[j], gf = gp[j + H2], gg = gp[j + 2 * H2], go = gp[j + 3 * H2];
            float cp = c_prev[b * H2 + j];
            cv = sigmoidf_(gf) * cp + sigmoidf_(gi) * tanhf(gg);
            hv = sigmoidf_(go) * tanhf(cv);
        }
        hsl[br][j] = hv;
        if (chunk == 0) {
            c_cur[b * H2 + j] = cv;
            if (t >= 1) Qout[(long)(b * LQQ + (t - 1)) * H2 + j] = hv;
        }
    }
    if (t == LQQ) return;
    __syncthreads();

    int n = chunk * 64 + (tid & 63);
    int r2 = (tid >> 6) * 2;
    float a0 = 0.f, a1 = 0.f;
#pragma unroll 8
    for (int k = 0; k < H2; k++) {
        float w = wt_d[(long)k * G8 + n];
        a0 += hsl[r2 + 0][k] * w;
        a1 += hsl[r2 + 1][k] * w;
    }
    int b = b0 + r2;
    g_cur[(long)b * G8 + n]       = xg_d[(long)(b * LQQ + t) * G8 + n] + a0;
    g_cur[(long)(b + 1) * G8 + n] = xg_d[(long)((b + 1) * LQQ + t) * G8 + n] + a1;
}

// ---------------- attention + concat[ctx, Q] ---------------------------------
__global__ __launch_bounds__(256)
void attention_kernel(const float* __restrict__ Qm, const float* __restrict__ Km,
                      const float* __restrict__ Vm, const int* __restrict__ source,
                      float* __restrict__ concatBuf) {
    int b = blockIdx.x >> 6;
    int q = blockIdx.x & 63;
    int tid = threadIdx.x;
    __shared__ float qrow[H2];
    __shared__ float part[LKK][4];
    __shared__ float aw[LKK];

    for (int i = tid; i < H2; i += 256) qrow[i] = Qm[(long)(b * LQQ + q) * H2 + i];
    __syncthreads();

    int k = tid >> 2, p = tid & 3;
    {
        const float* krow = Km + (long)(b * LKK + k) * H2 + p * 256;
        const float* qp = qrow + p * 256;
        float s = 0.f;
#pragma unroll 4
        for (int i = 0; i < 256; i++) s += qp[i] * krow[i];
        part[k][p] = s;
    }
    __syncthreads();
    if (tid < 64) {
        float sc = part[tid][0] + part[tid][1] + part[tid][2] + part[tid][3];
        bool masked = (source[b * LKK + tid] == 0);
        float m = masked ? -INFINITY : sc;
#pragma unroll
        for (int o = 32; o >= 1; o >>= 1) m = fmaxf(m, __shfl_xor(m, o, 64));
        float e = masked ? 0.f : expf(sc - m);
        float sum = e;
#pragma unroll
        for (int o = 32; o >= 1; o >>= 1) sum += __shfl_xor(sum, o, 64);
        aw[tid] = e / sum;
    }
    __syncthreads();

    for (int c = tid; c < H2; c += 256) {
        float acc = 0.f;
#pragma unroll 8
        for (int kk = 0; kk < LKK; kk++) acc += aw[kk] * Vm[(long)(b * LKK + kk) * H2 + c];
        long row = (long)(b * LQQ + q) * (2 * H2);
        concatBuf[row + c] = acc;
        concatBuf[row + H2 + c] = qrow[c];
    }
}

// ---------------- host launcher ----------------------------------------------
extern "C" void kernel_launch(void* const* d_in, const int* in_sizes, int n_in,
                              void* d_out, int out_size, void* d_ws, size_t ws_size,
                              hipStream_t stream) {
    const int*   src       = (const int*)  d_in[0];
    const int*   prev      = (const int*)  d_in[1];
    const float* emb       = (const float*)d_in[2];
    const float* enc_f_Wih = (const float*)d_in[3];
    const float* enc_f_Whh = (const float*)d_in[4];
    const float* enc_f_b   = (const float*)d_in[5];
    const float* enc_b_Wih = (const float*)d_in[6];
    const float* enc_b_Whh = (const float*)d_in[7];
    const float* enc_b_b   = (const float*)d_in[8];
    const float* dec_Wih   = (const float*)d_in[9];
    const float* dec_Whh   = (const float*)d_in[10];
    const float* dec_b     = (const float*)d_in[11];
    const float* k_W  = (const float*)d_in[12];
    const float* k_b  = (const float*)d_in[13];
    const float* v_W  = (const float*)d_in[14];
    const float* v_b  = (const float*)d_in[15];
    const float* fc1_W = (const float*)d_in[16];
    const float* fc1_b = (const float*)d_in[17];
    const float* fc2_W = (const float*)d_in[18];
    const float* fc2_b = (const float*)d_in[19];
    float* out = (float*)d_out;

    // workspace layout (floats) — union of coop + fallback paths (~90 MB)
    float* p = (float*)d_ws;
    float* xg_f    = p; p += (long)BB * LKK * G4;
    float* xg_b    = p; p += (long)BB * LKK * G4;
    float* xg_d    = p; p += (long)BB * LQQ * G8;
    float* enc_out = p; p += (long)BB * LKK * H2;
    float* encc    = p; p += 2L * BB * HH;
    float* hg_enc  = p; p += 2L * 2 * HH * 16;
    float* hg_dec  = p; p += 2L * H2 * 16;
    float* Qbuf    = p; p += (long)BB * LQQ * H2;
    float* Kbuf    = p; p += (long)BB * LKK * H2;
    float* Vbuf    = p; p += (long)BB * LKK * H2;
    float* concatB = p; p += (long)BB * LQQ * 2 * H2;
    float* fc1out  = p; p += (long)BB * LQQ * H2;
    float* wt_f    = p; p += (long)HH * G4;      // fallback only
    float* wt_b    = p; p += (long)HH * G4;
    float* wt_d    = p; p += (long)H2 * G8;
    float* enc_g   = p; p += 2L * 2 * BB * G4;
    float* enc_c   = p; p += 2L * 2 * BB * HH;
    float* dec_g   = p; p += 2L * BB * G8;
    float* dec_c   = p; p += 2L * BB * H2;
    int*   rev     = (int*)p; p += (BB * LKK);
    unsigned* bars = (unsigned*)p; p += 2;

    // 1) reversed source indices + barrier-counter zero
    rev_idx_kernel<<<4, 256, 0, stream>>>(src, rev, bars);

    // 2) xg precomputes (gathered-embedding GEMMs)
    gemm_nt_kernel<<<dim3(16, G4 / 64), 256, 0, stream>>>(emb, src, DD, enc_f_Wih, DD,
                                                          enc_f_b, xg_f, G4, G4, DD, 0);
    gemm_nt_kernel<<<dim3(16, G4 / 64), 256, 0, stream>>>(emb, rev, DD, enc_b_Wih, DD,
                                                          enc_b_b, xg_b, G4, G4, DD, 0);
    gemm_nt_kernel<<<dim3(16, G8 / 64), 256, 0, stream>>>(emb, prev, DD, dec_Wih, DD,
                                                          dec_b, xg_d, G8, G8, DD, 0);

    // 3) encoder recurrence: cooperative persistent kernel, else per-step fallback
    const float* cfin = encc;
    {
        unsigned* bar0 = bars;
        void* args[8];
        args[0] = (void*)&xg_f;      args[1] = (void*)&xg_b;
        args[2] = (void*)&enc_f_Whh; args[3] = (void*)&enc_b_Whh;
        args[4] = (void*)&hg_enc;    args[5] = (void*)&enc_out;
        args[6] = (void*)&encc;      args[7] = (void*)&bar0;
        hipError_t ce = hipLaunchCooperativeKernel(enc_recur, dim3(256), dim3(256),
                                                   args, 0, stream);
        if (ce != hipSuccess) {
            transpose_kernel<<<(G4 * HH + 255) / 256, 256, 0, stream>>>(enc_f_Whh, wt_f, G4, HH);
            transpose_kernel<<<(G4 * HH + 255) / 256, 256, 0, stream>>>(enc_b_Whh, wt_b, G4, HH);
            for (int t = 0; t <= LKK; t++) {
                const float* gp = enc_g + (long)((t + 1) & 1) * 2 * BB * G4;
                float*       gc = enc_g + (long)(t & 1) * 2 * BB * G4;
                const float* cp = enc_c + (long)((t + 1) & 1) * 2 * BB * HH;
                float*       cc = enc_c + (long)(t & 1) * 2 * BB * HH;
                enc_step_kernel<<<64, 256, 0, stream>>>(xg_f, xg_b, wt_f, wt_b, gp, gc,
                                                        cp, cc, enc_out, t);
            }
            cfin = enc_c;   // t=64 wrote ping-pong slot 0 (same layout as encc)
        }
    }

    // 4) K/V projections
    gemm_nt_kernel<<<dim3(16, 16), 256, 0, stream>>>(enc_out, nullptr, H2, k_W, H2,
                                                     k_b, Kbuf, H2, H2, H2, 0);
    gemm_nt_kernel<<<dim3(16, 16), 256, 0, stream>>>(enc_out, nullptr, H2, v_W, H2,
                                                     v_b, Vbuf, H2, H2, H2, 0);

    // 5) decoder recurrence: cooperative persistent kernel, else per-step fallback
    {
        unsigned* bar1 = bars + 1;
        void* args[7];
        args[0] = (void*)&xg_d;    args[1] = (void*)&dec_Whh;
        args[2] = (void*)&enc_out; args[3] = (void*)&cfin;
        args[4] = (void*)&hg_dec;  args[5] = (void*)&Qbuf;
        args[6] = (void*)&bar1;
        hipError_t cd = hipLaunchCooperativeKernel(dec_recur, dim3(256), dim3(256),
                                                   args, 0, stream);
        if (cd != hipSuccess) {
            transpose_kernel<<<(G8 * H2 + 255) / 256, 256, 0, stream>>>(dec_Whh, wt_d, G8, H2);
            for (int t = 0; t <= LQQ; t++) {
                const float* gp = dec_g + (long)((t + 1) & 1) * BB * G8;
                float*       gc = dec_g + (long)(t & 1) * BB * G8;
                const float* cp = dec_c + (long)((t + 1) & 1) * BB * H2;
                float*       cc = dec_c + (long)(t & 1) * BB * H2;
                dec_step_kernel<<<128, 256, 0, stream>>>(xg_d, wt_d, gp, gc, cp, cc,
                                                         enc_out, cfin, Qbuf, t);
            }
        }
    }

    // 6) attention -> concat[ctx, Q]
    attention_kernel<<<BB * LQQ, 256, 0, stream>>>(Qbuf, Kbuf, Vbuf, src, concatB);

    // 7) fc1 with tanh
    gemm_nt_kernel<<<dim3(16, 16), 256, 0, stream>>>(concatB, nullptr, 2 * H2, fc1_W, 2 * H2,
                                                     fc1_b, fc1out, H2, H2, 2 * H2, 1);

    // 8) fc2 -> output [1024, 10000]
    gemm_nt_kernel<<<dim3(16, (VV + 63) / 64), 256, 0, stream>>>(fc1out, nullptr, H2, fc2_W, H2,
                                                                 fc2_b, out, VV, VV, H2, 0);
}

// Round 5
// 2658.781 us; speedup vs baseline: 3.7923x; 1.0668x over previous
//
#include <hip/hip_runtime.h>
#include <cmath>

// Problem constants
#define BB   16
#define LKK  64
#define LQQ  64
#define DD   300
#define HH   512
#define H2   1024
#define G4   2048
#define G8   4096
#define VV   10000

__device__ __forceinline__ float sigmoidf_(float x) { return 1.f / (1.f + expf(-x)); }

// ---- agent-scope (cross-XCD coherent) scalar access ----
__device__ __forceinline__ float ld_sc(const float* p) {
    return __hip_atomic_load(p, __ATOMIC_RELAXED, __HIP_MEMORY_SCOPE_AGENT);
}
__device__ __forceinline__ void st_sc(float* p, float v) {
    __hip_atomic_store(p, v, __ATOMIC_RELAXED, __HIP_MEMORY_SCOPE_AGENT);
}

// ---- contention-free grid barrier: per-wg flag stores (no RMW serialization),
// wave-0 polls all 256 flags. Data written with st_sc + vmcnt(0) drain before
// the flag store => any wg observing flag==target also observes the data.
__device__ __forceinline__ void gbar2(unsigned* flags, int wg, unsigned target) {
    asm volatile("s_waitcnt vmcnt(0)" ::: "memory");
    if (threadIdx.x == 0)
        __hip_atomic_store(&flags[wg], target, __ATOMIC_RELAXED, __HIP_MEMORY_SCOPE_AGENT);
    if (threadIdx.x < 64) {
        for (;;) {
            unsigned mn = 0xffffffffu;
#pragma unroll
            for (int u = 0; u < 4; u++) {
                unsigned f = __hip_atomic_load(&flags[(threadIdx.x << 2) + u],
                                               __ATOMIC_RELAXED, __HIP_MEMORY_SCOPE_AGENT);
                mn = f < mn ? f : mn;
            }
            if (__all((int)(mn >= target))) break;
            __builtin_amdgcn_s_sleep(1);
        }
    }
    __syncthreads();
}

// ---------------- reverse source indices + barrier-flag init -----------------
__global__ void rev_idx_kernel(const int* __restrict__ src, int* __restrict__ rev,
                               unsigned* __restrict__ bars) {
    int tid = blockIdx.x * blockDim.x + threadIdx.x;
    if (tid < 512) bars[tid] = 0u;
    if (tid < BB * LKK) {
        int b = tid / LKK, t = tid % LKK;
        rev[tid] = src[b * LKK + (LKK - 1 - t)];
    }
}

// ---------------- transpose (fallback path): out[k*N+n] = in[n*K+k] ----------
__global__ void transpose_kernel(const float* __restrict__ in, float* __restrict__ out,
                                 int N, int K) {
    long tid = (long)blockIdx.x * blockDim.x + threadIdx.x;
    long total = (long)N * K;
    if (tid < total) {
        int n = (int)(tid % N);
        int k = (int)(tid / N);
        out[(long)k * N + n] = in[(long)n * K + k];
    }
}

// ---------------- 128x128-tile NT GEMM ---------------------------------------
// C[m,n] = sum_k A[m,k]*Bw[n,k] + bias[n]; A row-major [M,K] (or gathered via
// gidx); Bw row-major [N,K]. M must be a multiple of 128 (always 1024 here).
// Block 256 thr; 8x8 acc/thread as 2x2 blocks of 4x4 (rows tm*4+i / 64+tm*4+i,
// cols tn*4+j / 64+tn*4+j). act: 0=none, 1=tanh.
__global__ __launch_bounds__(256)
void gemm_nt128(const float* __restrict__ A, const int* __restrict__ gidx, int lda,
                const float* __restrict__ Bw, int ldb,
                const float* __restrict__ bias,
                float* __restrict__ C, int ldc,
                int N, int K, int act) {
    __shared__ float As[16][128];
    __shared__ float Bs[16][128];
    int m0 = blockIdx.x * 128;
    int n0 = blockIdx.y * 128;
    int tid = threadIdx.x;
    int tm = tid >> 4, tn = tid & 15;

    int srow = tid & 127;           // staging row within tile
    int kq   = (tid >> 7) * 8;      // 0 or 8
    long abase;
    {
        int gm = m0 + srow;
        abase = gidx ? (long)gidx[gm] * lda : (long)gm * lda;
    }
    int gn = n0 + srow;
    bool bvalid = gn < N;
    long bbase = (long)gn * ldb;

    float acc[8][8];
#pragma unroll
    for (int i = 0; i < 8; i++)
#pragma unroll
        for (int j = 0; j < 8; j++) acc[i][j] = 0.f;

    for (int k0 = 0; k0 < K; k0 += 16) {
        float va[8], vb[8];
        int kb = k0 + kq;
        if (kb + 8 <= K) {
            float4 t0 = *(const float4*)(A + abase + kb);
            float4 t1 = *(const float4*)(A + abase + kb + 4);
            va[0] = t0.x; va[1] = t0.y; va[2] = t0.z; va[3] = t0.w;
            va[4] = t1.x; va[5] = t1.y; va[6] = t1.z; va[7] = t1.w;
            if (bvalid) {
                float4 u0 = *(const float4*)(Bw + bbase + kb);
                float4 u1 = *(const float4*)(Bw + bbase + kb + 4);
                vb[0] = u0.x; vb[1] = u0.y; vb[2] = u0.z; vb[3] = u0.w;
                vb[4] = u1.x; vb[5] = u1.y; vb[6] = u1.z; vb[7] = u1.w;
            } else {
#pragma unroll
                for (int c = 0; c < 8; c++) vb[c] = 0.f;
            }
        } else {
#pragma unroll
            for (int c = 0; c < 8; c++) {
                int k = kb + c;
                va[c] = (k < K) ? A[abase + k] : 0.f;
                vb[c] = (bvalid && k < K) ? Bw[bbase + k] : 0.f;
            }
        }
#pragma unroll
        for (int c = 0; c < 8; c++) {
            As[kq + c][srow] = va[c];
            Bs[kq + c][srow] = vb[c];
        }
        __syncthreads();
#pragma unroll
        for (int k = 0; k < 16; k++) {
            float4 a0 = *(const float4*)&As[k][tm * 4];
            float4 a1 = *(const float4*)&As[k][64 + tm * 4];
            float4 b0 = *(const float4*)&Bs[k][tn * 4];
            float4 b1 = *(const float4*)&Bs[k][64 + tn * 4];
            float av[8] = {a0.x, a0.y, a0.z, a0.w, a1.x, a1.y, a1.z, a1.w};
            float bv[8] = {b0.x, b0.y, b0.z, b0.w, b1.x, b1.y, b1.z, b1.w};
#pragma unroll
            for (int i = 0; i < 8; i++)
#pragma unroll
                for (int j = 0; j < 8; j++) acc[i][j] += av[i] * bv[j];
        }
        __syncthreads();
    }
#pragma unroll
    for (int i = 0; i < 8; i++) {
        int m = m0 + ((i < 4) ? (tm * 4 + i) : (64 + tm * 4 + i - 4));
#pragma unroll
        for (int j = 0; j < 8; j++) {
            int n = n0 + ((j < 4) ? (tn * 4 + j) : (64 + tn * 4 + j - 4));
            if (n < N) {
                float v = acc[i][j] + bias[n];
                if (act == 1) v = tanhf(v);
                C[(long)m * ldc + n] = v;
            }
        }
    }
}

// ============ persistent encoder recurrence (fwd+bwd), cooperative ==========
__global__ __launch_bounds__(256, 1)
void enc_recur(const float* __restrict__ xg_f, const float* __restrict__ xg_b,
               const float* __restrict__ Wf, const float* __restrict__ Wb,
               float* __restrict__ hglob, float* __restrict__ enc_out,
               float* __restrict__ encc, unsigned* __restrict__ flags) {
    __shared__ float hs[HH * 16];       // 32 KB
    __shared__ float gbuf[BB * 17];
    int wg  = blockIdx.x;
    int dir = wg >> 7;
    int j0  = (wg & 127) * 4;
    int tid = threadIdx.x;
    int ks   = tid & 31;
    int tile = tid >> 5;
    int bh   = tile >> 2;
    int nql  = (tile & 3) << 2;
    int gate = nql >> 2;
    int sw   = (ks >> 2) & 3;
    const float* W  = dir ? Wb : Wf;    // [2048][512]
    const float* xg = dir ? xg_b : xg_f;

    float wreg[4][16];
#pragma unroll
    for (int jn = 0; jn < 4; jn++) {
        const float* wrow = W + (long)(gate * HH + j0 + jn) * HH;
#pragma unroll
        for (int j = 0; j < 16; j++) wreg[jn][j] = wrow[ks + 32 * j];
    }

    int ub = tid & 15, ujj = tid >> 4;
    float creg = 0.f;
    float4* hsv = (float4*)hs;

    for (int t = 0; t < LKK; t++) {
        if (t == 0) {
            for (int i = tid; i < HH * 16; i += 256) hs[i] = 0.f;
        } else {
            const float* hg = hglob + (long)((dir << 1) | (t & 1)) * (HH * 16);
            float vv[32];
#pragma unroll
            for (int u = 0; u < 32; u++) vv[u] = ld_sc(hg + tid + u * 256);
#pragma unroll
            for (int u = 0; u < 32; u++) {
                int e = tid + u * 256;
                int jj = e >> 4, b = e & 15;
                hs[(jj << 4) + ((((b >> 2) ^ ((jj >> 2) & 3))) << 2) + (b & 3)] = vv[u];
            }
        }
        float4 xr[8];
        if (ks == 0) {
#pragma unroll
            for (int i = 0; i < 8; i++) {
                const float* xp = xg + (long)((bh * 8 + i) * LKK + t) * G4 + gate * HH + j0;
                xr[i] = *(const float4*)xp;
            }
        }
        __syncthreads();

        float acc[8][4];
#pragma unroll
        for (int i = 0; i < 8; i++)
#pragma unroll
            for (int jn = 0; jn < 4; jn++) acc[i][jn] = 0.f;
#pragma unroll
        for (int j = 0; j < 16; j++) {
            int k = ks + 32 * j;
            float4 h0 = hsv[k * 4 + ((bh * 2 + 0) ^ sw)];
            float4 h1 = hsv[k * 4 + ((bh * 2 + 1) ^ sw)];
#pragma unroll
            for (int jn = 0; jn < 4; jn++) {
                float w = wreg[jn][j];
                acc[0][jn] += h0.x * w; acc[1][jn] += h0.y * w;
                acc[2][jn] += h0.z * w; acc[3][jn] += h0.w * w;
                acc[4][jn] += h1.x * w; acc[5][jn] += h1.y * w;
                acc[6][jn] += h1.z * w; acc[7][jn] += h1.w * w;
            }
        }
#pragma unroll
        for (int i = 0; i < 8; i++)
#pragma unroll
            for (int jn = 0; jn < 4; jn++) {
                float v = acc[i][jn];
                v += __shfl_xor(v, 1, 64);  v += __shfl_xor(v, 2, 64);
                v += __shfl_xor(v, 4, 64);  v += __shfl_xor(v, 8, 64);
                v += __shfl_xor(v, 16, 64);
                acc[i][jn] = v;
            }
        if (ks == 0) {
#pragma unroll
            for (int i = 0; i < 8; i++)
#pragma unroll
                for (int jn = 0; jn < 4; jn++)
                    gbuf[(bh * 8 + i) * 17 + nql + jn] = acc[i][jn] + ((const float*)&xr[i])[jn];
        }
        __syncthreads();

        if (tid < 64) {
            int j = j0 + ujj;
            float gi = gbuf[ub * 17 + 0  + ujj];
            float gf = gbuf[ub * 17 + 4  + ujj];
            float gg = gbuf[ub * 17 + 8  + ujj];
            float go = gbuf[ub * 17 + 12 + ujj];
            float cv = sigmoidf_(gf) * creg + sigmoidf_(gi) * tanhf(gg);
            creg = cv;
            float hv = sigmoidf_(go) * tanhf(cv);
            st_sc(&hglob[(long)((dir << 1) | ((t + 1) & 1)) * (HH * 16) + j * 16 + ub], hv);
            int kpos = dir ? (LKK - 1 - t) : t;
            enc_out[(long)(ub * LKK + kpos) * H2 + dir * HH + j] = hv;
            if (t == LKK - 1) encc[(dir * BB + ub) * HH + j] = creg;
        }
        if (t < LKK - 1) gbar2(flags, wg, (unsigned)(t + 1));
    }
}

// ============ persistent decoder recurrence, cooperative ====================
__global__ __launch_bounds__(256, 1)
void dec_recur(const float* __restrict__ xg_d, const float* __restrict__ Wd,
               const float* __restrict__ enc_out, const float* __restrict__ encc,
               float* __restrict__ hglob, float* __restrict__ Qout,
               unsigned* __restrict__ flags) {
    __shared__ float hs[HH * 16];       // 32 KB (one half of h)
    __shared__ float gbuf[BB * 17];
    int wg  = blockIdx.x;
    int j0  = wg * 4;
    int tid = threadIdx.x;
    int ks   = tid & 31;
    int tile = tid >> 5;
    int bh   = tile >> 2;
    int nql  = (tile & 3) << 2;
    int gate = nql >> 2;
    int sw   = (ks >> 2) & 3;

    float wreg[4][32];
#pragma unroll
    for (int jn = 0; jn < 4; jn++) {
        const float* wrow = Wd + (long)(gate * H2 + j0 + jn) * H2;
#pragma unroll
        for (int j = 0; j < 32; j++) wreg[jn][j] = wrow[ks + 32 * j];
    }

    int ub = tid & 15, ujj = tid >> 4;
    float creg = 0.f;
    if (tid < 64) {
        int j = j0 + ujj;
        creg = ((j & 1) == 0) ? encc[ub * HH + (j >> 1)]
                              : encc[(BB + ub) * HH + (j >> 1)];
    }
    float4* hsv = (float4*)hs;

    for (int t = 0; t < LQQ; t++) {
        float4 xr[8];
        if (ks == 0) {
#pragma unroll
            for (int i = 0; i < 8; i++) {
                const float* xp = xg_d + (long)((bh * 8 + i) * LQQ + t) * G8 + gate * H2 + j0;
                xr[i] = *(const float4*)xp;
            }
        }
        float acc[8][4];
#pragma unroll
        for (int i = 0; i < 8; i++)
#pragma unroll
            for (int jn = 0; jn < 4; jn++) acc[i][jn] = 0.f;

#pragma unroll
        for (int half = 0; half < 2; half++) {
            if (t == 0) {
                for (int e = tid; e < HH * 16; e += 256) {
                    int kl = e >> 4, b = e & 15;
                    int k = half * HH + kl;
                    float hv = ((k & 1) == 0)
                        ? enc_out[(long)(b * LKK + (LKK - 1)) * H2 + (k >> 1)]
                        : enc_out[(long)(b * LKK) * H2 + HH + (k >> 1)];
                    hs[(kl << 4) + ((((b >> 2) ^ ((kl >> 2) & 3))) << 2) + (b & 3)] = hv;
                }
            } else {
                const float* hg = hglob + (long)(t & 1) * (H2 * 16) + (long)half * (HH * 16);
                float vv[32];
#pragma unroll
                for (int u = 0; u < 32; u++) vv[u] = ld_sc(hg + tid + u * 256);
#pragma unroll
                for (int u = 0; u < 32; u++) {
                    int e = tid + u * 256;
                    int kl = e >> 4, b = e & 15;
                    hs[(kl << 4) + ((((b >> 2) ^ ((kl >> 2) & 3))) << 2) + (b & 3)] = vv[u];
                }
            }
            __syncthreads();
#pragma unroll
            for (int jj2 = 0; jj2 < 16; jj2++) {
                int j = half * 16 + jj2;
                int kl = ks + 32 * jj2;
                float4 h0 = hsv[kl * 4 + ((bh * 2 + 0) ^ sw)];
                float4 h1 = hsv[kl * 4 + ((bh * 2 + 1) ^ sw)];
#pragma unroll
                for (int jn = 0; jn < 4; jn++) {
                    float w = wreg[jn][j];
                    acc[0][jn] += h0.x * w; acc[1][jn] += h0.y * w;
                    acc[2][jn] += h0.z * w; acc[3][jn] += h0.w * w;
                    acc[4][jn] += h1.x * w; acc[5][jn] += h1.y * w;
                    acc[6][jn] += h1.z * w; acc[7][jn] += h1.w * w;
                }
            }
            __syncthreads();
        }

#pragma unroll
        for (int i = 0; i < 8; i++)
#pragma unroll
            for (int jn = 0; jn < 4; jn++) {
                float v = acc[i][jn];
                v += __shfl_xor(v, 1, 64);  v += __shfl_xor(v, 2, 64);
                v += __shfl_xor(v, 4, 64);  v += __shfl_xor(v, 8, 64);
                v += __shfl_xor(v, 16, 64);
                acc[i][jn] = v;
            }
        if (ks == 0) {
#pragma unroll
            for (int i = 0; i < 8; i++)
#pragma unroll
                for (int jn = 0; jn < 4; jn++)
                    gbuf[(bh * 8 + i) * 17 + nql + jn] = acc[i][jn] + ((const float*)&xr[i])[jn];
        }
        __syncthreads();

        if (tid < 64) {
            int j = j0 + ujj;
            float gi = gbuf[ub * 17 + 0  + ujj];
            float gf = gbuf[ub * 17 + 4  + ujj];
            float gg = gbuf[ub * 17 + 8  + ujj];
            float go = gbuf[ub * 17 + 12 + ujj];
            float cv = sigmoidf_(gf) * creg + sigmoidf_(gi) * tanhf(gg);
            creg = cv;
            float hv = sigmoidf_(go) * tanhf(cv);
            st_sc(&hglob[(long)((t + 1) & 1) * (H2 * 16) + j * 16 + ub], hv);
            Qout[(long)(ub * LQQ + t) * H2 + j] = hv;
        }
        if (t < LQQ - 1) gbar2(flags, wg, (unsigned)(t + 1));
    }
}

// ============ fallback per-step kernels (known-good) ========================
__global__ __launch_bounds__(256)
void enc_step_kernel(const float* __restrict__ xg_f, const float* __restrict__ xg_b,
                     const float* __restrict__ wt_f, const float* __restrict__ wt_b,
                     const float* __restrict__ g_prev, float* __restrict__ g_cur,
                     const float* __restrict__ c_prev, float* __restrict__ c_cur,
                     float* __restrict__ enc_out, int t) {
    int dir = blockIdx.x >> 5;
    int chunk = blockIdx.x & 31;
    int tid = threadIdx.x;
    __shared__ float hsl[BB][HH];

    for (int e = tid; e < BB * HH; e += 256) {
        int b = e >> 9, j = e & (HH - 1);
        float hv, cv;
        if (t == 0) { hv = 0.f; cv = 0.f; }
        else {
            const float* gp = g_prev + (long)(dir * BB + b) * G4;
            float gi = gp[j], gf = gp[j + HH], gg = gp[j + 2 * HH], go = gp[j + 3 * HH];
            float cp = c_prev[(dir * BB + b) * HH + j];
            cv = sigmoidf_(gf) * cp + sigmoidf_(gi) * tanhf(gg);
            hv = sigmoidf_(go) * tanhf(cv);
        }
        hsl[b][j] = hv;
        if (chunk == 0) {
            c_cur[(dir * BB + b) * HH + j] = cv;
            if (t >= 1) {
                int s = t - 1;
                int kpos = (dir == 0) ? s : (LKK - 1 - s);
                enc_out[(long)(b * LKK + kpos) * H2 + dir * HH + j] = hv;
            }
        }
    }
    if (t == LKK) return;
    __syncthreads();

    const float* wt = dir ? wt_b : wt_f;
    const float* xg = dir ? xg_b : xg_f;
    int n = chunk * 64 + (tid & 63);
    int rb = (tid >> 6) * 4;
    float a0 = 0.f, a1 = 0.f, a2 = 0.f, a3 = 0.f;
#pragma unroll 8
    for (int k = 0; k < HH; k++) {
        float w = wt[(long)k * G4 + n];
        a0 += hsl[rb + 0][k] * w;
        a1 += hsl[rb + 1][k] * w;
        a2 += hsl[rb + 2][k] * w;
        a3 += hsl[rb + 3][k] * w;
    }
    g_cur[(long)(dir * BB + rb + 0) * G4 + n] = xg[(long)((rb + 0) * LKK + t) * G4 + n] + a0;
    g_cur[(long)(dir * BB + rb + 1) * G4 + n] = xg[(long)((rb + 1) * LKK + t) * G4 + n] + a1;
    g_cur[(long)(dir * BB + rb + 2) * G4 + n] = xg[(long)((rb + 2) * LKK + t) * G4 + n] + a2;
    g_cur[(long)(dir * BB + rb + 3) * G4 + n] = xg[(long)((rb + 3) * LKK + t) * G4 + n] + a3;
}

__global__ __launch_bounds__(256)
void dec_step_kernel(const float* __restrict__ xg_d, const float* __restrict__ wt_d,
                     const float* __restrict__ g_prev, float* __restrict__ g_cur,
                     const float* __restrict__ c_prev, float* __restrict__ c_cur,
                     const float* __restrict__ enc_out, const float* __restrict__ enc_c_fin,
                     float* __restrict__ Qout, int t) {
    int rh = blockIdx.x >> 6;
    int chunk = blockIdx.x & 63;
    int tid = threadIdx.x;
    int b0 = rh * 8;
    __shared__ float hsl[8][H2];

    for (int e = tid; e < 8 * H2; e += 256) {
        int br = e >> 10, j = e & (H2 - 1);
        int b = b0 + br;
        float hv, cv;
        if (t == 0) {
            int jj = j >> 1;
            if ((j & 1) == 0) {
                hv = enc_out[(long)(b * LKK + (LKK - 1)) * H2 + jj];
                cv = enc_c_fin[(0 * BB + b) * HH + jj];
            } else {
                hv = enc_out[(long)(b * LKK + 0) * H2 + HH + jj];
                cv = enc_c_fin[(1 * BB + b) * HH + jj];
            }
        } else {
            const float* gp = g_prev + (long)b * G8;
            float gi = gp[j], gf = gp[j + H2], gg = gp[j + 2 * H2], go = gp[j + 3 * H2];
            float cp = c_prev[b * H2 + j];
            cv = sigmoidf_(gf) * cp + sigmoidf_(gi) * tanhf(gg);
            hv = sigmoidf_(go) * tanhf(cv);
        }
        hsl[br][j] = hv;
        if (chunk == 0) {
            c_cur[b * H2 + j] = cv;
            if (t >= 1) Qout[(long)(b * LQQ + (t - 1)) * H2 + j] = hv;
        }
    }
    if (t == LQQ) return;
    __syncthreads();

    int n = chunk * 64 + (tid & 63);
    int r2 = (tid >> 6) * 2;
    float a0 = 0.f, a1 = 0.f;
#pragma unroll 8
    for (int k = 0; k < H2; k++) {
        float w = wt_d[(long)k * G8 + n];
        a0 += hsl[r2 + 0][k] * w;
        a1 += hsl[r2 + 1][k] * w;
    }
    int b = b0 + r2;
    g_cur[(long)b * G8 + n]       = xg_d[(long)(b * LQQ + t) * G8 + n] + a0;
    g_cur[(long)(b + 1) * G8 + n] = xg_d[(long)((b + 1) * LQQ + t) * G8 + n] + a1;
}

// ---------------- attention + concat[ctx, Q] ---------------------------------
__global__ __launch_bounds__(256)
void attention_kernel(const float* __restrict__ Qm, const float* __restrict__ Km,
                      const float* __restrict__ Vm, const int* __restrict__ source,
                      float* __restrict__ concatBuf) {
    int b = blockIdx.x >> 6;
    int q = blockIdx.x & 63;
    int tid = threadIdx.x;
    __shared__ float qrow[H2];
    __shared__ float part[LKK][4];
    __shared__ float aw[LKK];

    for (int i = tid; i < H2; i += 256) qrow[i] = Qm[(long)(b * LQQ + q) * H2 + i];
    __syncthreads();

    int k = tid >> 2, p = tid & 3;
    {
        const float* krow = Km + (long)(b * LKK + k) * H2 + p * 256;
        const float* qp = qrow + p * 256;
        float s = 0.f;
#pragma unroll 4
        for (int i = 0; i < 256; i++) s += qp[i] * krow[i];
        part[k][p] = s;
    }
    __syncthreads();
    if (tid < 64) {
        float sc = part[tid][0] + part[tid][1] + part[tid][2] + part[tid][3];
        bool masked = (source[b * LKK + tid] == 0);
        float m = masked ? -INFINITY : sc;
#pragma unroll
        for (int o = 32; o >= 1; o >>= 1) m = fmaxf(m, __shfl_xor(m, o, 64));
        float e = masked ? 0.f : expf(sc - m);
        float sum = e;
#pragma unroll
        for (int o = 32; o >= 1; o >>= 1) sum += __shfl_xor(sum, o, 64);
        aw[tid] = e / sum;
    }
    __syncthreads();

    for (int c = tid; c < H2; c += 256) {
        float acc = 0.f;
#pragma unroll 8
        for (int kk = 0; kk < LKK; kk++) acc += aw[kk] * Vm[(long)(b * LKK + kk) * H2 + c];
        long row = (long)(b * LQQ + q) * (2 * H2);
        concatBuf[row + c] = acc;
        concatBuf[row + H2 + c] = qrow[c];
    }
}

// ---------------- host launcher ----------------------------------------------
extern "C" void kernel_launch(void* const* d_in, const int* in_sizes, int n_in,
                              void* d_out, int out_size, void* d_ws, size_t ws_size,
                              hipStream_t stream) {
    const int*   src       = (const int*)  d_in[0];
    const int*   prev      = (const int*)  d_in[1];
    const float* emb       = (const float*)d_in[2];
    const float* enc_f_Wih = (const float*)d_in[3];
    const float* enc_f_Whh = (const float*)d_in[4];
    const float* enc_f_b   = (const float*)d_in[5];
    const float* enc_b_Wih = (const float*)d_in[6];
    const float* enc_b_Whh = (const float*)d_in[7];
    const float* enc_b_b   = (const float*)d_in[8];
    const float* dec_Wih   = (const float*)d_in[9];
    const float* dec_Whh   = (const float*)d_in[10];
    const float* dec_b     = (const float*)d_in[11];
    const float* k_W  = (const float*)d_in[12];
    const float* k_b  = (const float*)d_in[13];
    const float* v_W  = (const float*)d_in[14];
    const float* v_b  = (const float*)d_in[15];
    const float* fc1_W = (const float*)d_in[16];
    const float* fc1_b = (const float*)d_in[17];
    const float* fc2_W = (const float*)d_in[18];
    const float* fc2_b = (const float*)d_in[19];
    float* out = (float*)d_out;

    // workspace layout (floats) — union of coop + fallback paths (~90 MB)
    float* p = (float*)d_ws;
    float* xg_f    = p; p += (long)BB * LKK * G4;
    float* xg_b    = p; p += (long)BB * LKK * G4;
    float* xg_d    = p; p += (long)BB * LQQ * G8;
    float* enc_out = p; p += (long)BB * LKK * H2;
    float* encc    = p; p += 2L * BB * HH;
    float* hg_enc  = p; p += 2L * 2 * HH * 16;
    float* hg_dec  = p; p += 2L * H2 * 16;
    float* Qbuf    = p; p += (long)BB * LQQ * H2;
    float* Kbuf    = p; p += (long)BB * LKK * H2;
    float* Vbuf    = p; p += (long)BB * LKK * H2;
    float* concatB = p; p += (long)BB * LQQ * 2 * H2;
    float* fc1out  = p; p += (long)BB * LQQ * H2;
    float* wt_f    = p; p += (long)HH * G4;      // fallback only
    float* wt_b    = p; p += (long)HH * G4;
    float* wt_d    = p; p += (long)H2 * G8;
    float* enc_g   = p; p += 2L * 2 * BB * G4;
    float* enc_c   = p; p += 2L * 2 * BB * HH;
    float* dec_g   = p; p += 2L * BB * G8;
    float* dec_c   = p; p += 2L * BB * H2;
    int*   rev     = (int*)p; p += (BB * LKK);
    unsigned* bars = (unsigned*)p; p += 512;     // flags: enc [0:256), dec [256:512)

    // 1) reversed source indices + barrier-flag zero
    rev_idx_kernel<<<4, 256, 0, stream>>>(src, rev, bars);

    // 2) xg precomputes (gathered-embedding GEMMs), M = 1024
    gemm_nt128<<<dim3(8, G4 / 128), 256, 0, stream>>>(emb, src, DD, enc_f_Wih, DD,
                                                      enc_f_b, xg_f, G4, G4, DD, 0);
    gemm_nt128<<<dim3(8, G4 / 128), 256, 0, stream>>>(emb, rev, DD, enc_b_Wih, DD,
                                                      enc_b_b, xg_b, G4, G4, DD, 0);
    gemm_nt128<<<dim3(8, G8 / 128), 256, 0, stream>>>(emb, prev, DD, dec_Wih, DD,
                                                      dec_b, xg_d, G8, G8, DD, 0);

    // 3) encoder recurrence: cooperative persistent kernel, else per-step fallback
    const float* cfin = encc;
    {
        unsigned* fe = bars;
        void* args[8];
        args[0] = (void*)&xg_f;      args[1] = (void*)&xg_b;
        args[2] = (void*)&enc_f_Whh; args[3] = (void*)&enc_b_Whh;
        args[4] = (void*)&hg_enc;    args[5] = (void*)&enc_out;
        args[6] = (void*)&encc;      args[7] = (void*)&fe;
        hipError_t ce = hipLaunchCooperativeKernel(enc_recur, dim3(256), dim3(256),
                                                   args, 0, stream);
        if (ce != hipSuccess) {
            transpose_kernel<<<(G4 * HH + 255) / 256, 256, 0, stream>>>(enc_f_Whh, wt_f, G4, HH);
            transpose_kernel<<<(G4 * HH + 255) / 256, 256, 0, stream>>>(enc_b_Whh, wt_b, G4, HH);
            for (int t = 0; t <= LKK; t++) {
                const float* gp = enc_g + (long)((t + 1) & 1) * 2 * BB * G4;
                float*       gc = enc_g + (long)(t & 1) * 2 * BB * G4;
                const float* cp = enc_c + (long)((t + 1) & 1) * 2 * BB * HH;
                float*       cc = enc_c + (long)(t & 1) * 2 * BB * HH;
                enc_step_kernel<<<64, 256, 0, stream>>>(xg_f, xg_b, wt_f, wt_b, gp, gc,
                                                        cp, cc, enc_out, t);
            }
            cfin = enc_c;
        }
    }

    // 4) K/V projections
    gemm_nt128<<<dim3(8, 8), 256, 0, stream>>>(enc_out, nullptr, H2, k_W, H2,
                                               k_b, Kbuf, H2, H2, H2, 0);
    gemm_nt128<<<dim3(8, 8), 256, 0, stream>>>(enc_out, nullptr, H2, v_W, H2,
                                               v_b, Vbuf, H2, H2, H2, 0);

    // 5) decoder recurrence: cooperative persistent kernel, else per-step fallback
    {
        unsigned* fd = bars + 256;
        void* args[7];
        args[0] = (void*)&xg_d;    args[1] = (void*)&dec_Whh;
        args[2] = (void*)&enc_out; args[3] = (void*)&cfin;
        args[4] = (void*)&hg_dec;  args[5] = (void*)&Qbuf;
        args[6] = (void*)&fd;
        hipError_t cd = hipLaunchCooperativeKernel(dec_recur, dim3(256), dim3(256),
                                                   args, 0, stream);
        if (cd != hipSuccess) {
            transpose_kernel<<<(G8 * H2 + 255) / 256, 256, 0, stream>>>(dec_Whh, wt_d, G8, H2);
            for (int t = 0; t <= LQQ; t++) {
                const float* gp = dec_g + (long)((t + 1) & 1) * BB * G8;
                float*       gc = dec_g + (long)(t & 1) * BB * G8;
                const float* cp = dec_c + (long)((t + 1) & 1) * BB * H2;
                float*       cc = dec_c + (long)(t & 1) * BB * H2;
                dec_step_kernel<<<128, 256, 0, stream>>>(xg_d, wt_d, gp, gc, cp, cc,
                                                         enc_out, cfin, Qbuf, t);
            }
        }
    }

    // 6) attention -> concat[ctx, Q]
    attention_kernel<<<BB * LQQ, 256, 0, stream>>>(Qbuf, Kbuf, Vbuf, src, concatB);

    // 7) fc1 with tanh
    gemm_nt128<<<dim3(8, 8), 256, 0, stream>>>(concatB, nullptr, 2 * H2, fc1_W, 2 * H2,
                                               fc1_b, fc1out, H2, H2, 2 * H2, 1);

    // 8) fc2 -> output [1024, 10000]
    gemm_nt128<<<dim3(8, (VV + 127) / 128), 256, 0, stream>>>(fc1out, nullptr, H2, fc2_W, H2,
                                                              fc2_b, out, VV, VV, H2, 0);
}